// Round 3
// baseline (335.228 us; speedup 1.0000x reference)
//
#include <hip/hip_runtime.h>
#include <cstdint>
#include <cstddef>

#define BS 8
#define NQ 16384
#define NG 1024
#define NC 5
#define NBC 40
#define THREADS 256
#define GRID 512            // 2 blocks/CU on 256 CUs -> co-resident by construction
#define SEGS 16             // phase-0 scan segments per (b,c)
#define SLACK 0.1514214f    // 0.1*sqrt(2) + 0.01 margin
#define FINF 3.0e38f

using u64 = unsigned long long;

// ---------- float top-4 (keep 4 smallest, sorted ascending) ----------
__device__ __forceinline__ void fce(float &x, float &y) {
    float lo = fminf(x, y), hi = fmaxf(x, y);
    x = lo; y = hi;
}
__device__ __forceinline__ void finsert(float k[4], float v) {
    float c = v, t;
    t = fminf(k[0], c); c = fmaxf(k[0], c); k[0] = t;
    t = fminf(k[1], c); c = fmaxf(k[1], c); k[1] = t;
    t = fminf(k[2], c); c = fmaxf(k[2], c); k[2] = t;
    k[3] = fminf(k[3], c);
}
__device__ __forceinline__ void fmerge4(float a[4], float b0, float b1, float b2, float b3) {
    float m0 = fminf(a[0], b3), m1 = fminf(a[1], b2), m2 = fminf(a[2], b1), m3 = fminf(a[3], b0);
    fce(m0, m2); fce(m1, m3); fce(m0, m1); fce(m2, m3);
    a[0] = m0; a[1] = m1; a[2] = m2; a[3] = m3;
}

// ---------- u64 keyed top-4 (exact, tie-break by low 32 = q) ----------
__device__ __forceinline__ void ce(u64 &x, u64 &y) {
    u64 lo = x < y ? x : y;
    u64 hi = x < y ? y : x;
    x = lo; y = hi;
}
__device__ __forceinline__ void merge4(u64 a[4], u64 b0, u64 b1, u64 b2, u64 b3) {
    u64 m0 = a[0] < b3 ? a[0] : b3;
    u64 m1 = a[1] < b2 ? a[1] : b2;
    u64 m2 = a[2] < b1 ? a[2] : b1;
    u64 m3 = a[3] < b0 ? a[3] : b0;
    ce(m0, m2); ce(m1, m3); ce(m0, m1); ce(m2, m3);
    a[0] = m0; a[1] = m1; a[2] = m2; a[3] = m3;
}

#define SOFTMAX5(lg, X0, X1, X2, X3, X4, S)                                     \
    float X0 = (lg)[0], X1 = (lg)[1], X2 = (lg)[2], X3 = (lg)[3], X4 = (lg)[4]; \
    {                                                                           \
        float mx_ = fmaxf(fmaxf(fmaxf(X0, X1), fmaxf(X2, X3)), X4);             \
        X0 = expf(X0 - mx_); X1 = expf(X1 - mx_); X2 = expf(X2 - mx_);          \
        X3 = expf(X3 - mx_); X4 = expf(X4 - mx_);                               \
    }                                                                           \
    float S = X0 + X1 + X2 + X3 + X4;

// grid barrier: own counter per use, zeroed by memset node before the kernel.
__device__ __forceinline__ void gridbar(unsigned* ctr, int tid) {
    __threadfence();   // release my global writes to agent scope
    __syncthreads();
    if (tid == 0) {
        __hip_atomic_fetch_add(ctr, 1u, __ATOMIC_RELEASE, __HIP_MEMORY_SCOPE_AGENT);
        // bounded spin (safety net: ~0.3s worst case instead of infinite hang)
        for (long s = 0; s < (1L << 24); ++s) {
            if (__hip_atomic_load(ctr, __ATOMIC_ACQUIRE, __HIP_MEMORY_SCOPE_AGENT) >= GRID) break;
            __builtin_amdgcn_s_sleep(2);
        }
    }
    __syncthreads();
    __threadfence();   // acquire side: make remote writes visible to all lanes
}

__global__ __launch_bounds__(THREADS, 2) void fused_kernel(
        const float* __restrict__ pred_coords,   // [BS][NQ][2]
        const float* __restrict__ logits,        // [BS][NQ][NC]
        const float* __restrict__ gt_coords,     // [BS][NG][2]
        const int*   __restrict__ gt_labels,     // [BS][NG]
        const int*   __restrict__ gt_masks,      // [BS][NG]
        unsigned*    __restrict__ ctrs,          // [3] barrier counters (pre-zeroed)
        unsigned*    __restrict__ count,         // [NBC] candidate counts (pre-zeroed)
        float*       __restrict__ T,             // [NBC]
        float*       __restrict__ partials,      // [NBC*SEGS][4]
        float*       __restrict__ probs,         // [NBC][NQ]  (= [b][c][q])
        u64*         __restrict__ clist,         // [NBC][NQ]
        int*         __restrict__ out)           // [BS][4][NG]
{
    const int tid  = threadIdx.x;
    const int blk  = blockIdx.x;
    const int wv   = tid >> 6;
    const int lane = tid & 63;

    __shared__ float slds[4][4];

    // ---------------- phase 0: probs (class-major) + per-unit top-4 of p_c ----------------
    for (int u = blk; u < NBC * SEGS; u += GRID) {
        int bc  = u >> 4;                 // SEGS == 16
        int seg = u & (SEGS - 1);
        int b   = bc / NC, c = bc - b * NC;
        const float* lgb = logits + (size_t)b * NQ * NC;
        float* pr = probs + ((size_t)bc << 14);
        float nk[4] = {FINF, FINF, FINF, FINF};
        #pragma unroll
        for (int r = 0; r < 4; ++r) {
            int q = (seg << 10) + (r << 8) + tid;
            const float* lg = lgb + (size_t)q * NC;
            SOFTMAX5(lg, x0, x1, x2, x3, x4, s);
            float num = (c == 0) ? x0 : (c == 1) ? x1 : (c == 2) ? x2 : (c == 3) ? x3 : x4;
            float p = num / s;
            pr[q] = p;
            finsert(nk, -p);
        }
        #pragma unroll
        for (int d = 1; d < 64; d <<= 1) {
            float b0 = __shfl_xor(nk[0], d, 64);
            float b1 = __shfl_xor(nk[1], d, 64);
            float b2 = __shfl_xor(nk[2], d, 64);
            float b3 = __shfl_xor(nk[3], d, 64);
            fmerge4(nk, b0, b1, b2, b3);
        }
        if (lane == 0) {
            #pragma unroll
            for (int j = 0; j < 4; ++j) slds[wv][j] = nk[j];
        }
        __syncthreads();
        if (tid == 0) {
            #pragma unroll
            for (int w = 1; w < 4; ++w) fmerge4(nk, slds[w][0], slds[w][1], slds[w][2], slds[w][3]);
            #pragma unroll
            for (int j = 0; j < 4; ++j) partials[u * 4 + j] = nk[j];
        }
        __syncthreads();
    }

    gridbar(&ctrs[0], tid);

    // ---------------- phase 1: exact threshold per (b,c) ----------------
    if (blk < NBC && tid < 64) {
        float a[4] = {partials[blk * 64 + tid], FINF, FINF, FINF};  // 16 segs * 4 = 64 values
        #pragma unroll
        for (int d = 1; d < 64; d <<= 1) {
            float b0 = __shfl_xor(a[0], d, 64);
            float b1 = __shfl_xor(a[1], d, 64);
            float b2 = __shfl_xor(a[2], d, 64);
            float b3 = __shfl_xor(a[3], d, 64);
            fmerge4(a, b0, b1, b2, b3);
        }
        if (tid == 0) T[blk] = -a[3] - SLACK;   // P4* - slack
    }

    gridbar(&ctrs[1], tid);

    // ---------------- phase 2: ballot-compact candidates ----------------
    {
        int b = blk >> 6, chunk = blk & 63;
        int q = (chunk << 8) + tid;
        #pragma unroll
        for (int c = 0; c < NC; ++c) {
            int bc = b * NC + c;
            float p = probs[((size_t)bc << 14) + q];
            bool pass = (p >= T[bc]);
            u64 mask = __ballot(pass);
            if (mask) {
                unsigned base = 0;
                if (lane == 0)
                    base = __hip_atomic_fetch_add(&count[bc], (unsigned)__popcll(mask),
                                                  __ATOMIC_RELAXED, __HIP_MEMORY_SCOPE_AGENT);
                base = __shfl((int)base, 0, 64);
                if (pass) {
                    unsigned off = base + (unsigned)__popcll(mask & ((1ull << lane) - 1ull));
                    clist[((size_t)bc << 14) + off] = ((u64)__float_as_uint(p) << 32) | (unsigned)q;
                }
            }
        }
    }

    gridbar(&ctrs[2], tid);

    // ---------------- phase 3: exact keyed top-4 per gt (2 gts per wave) ----------------
    for (int grp = blk; grp < BS * NG / 8; grp += GRID) {
        int b  = grp >> 7;
        int g0 = (grp & 127) << 3;
        const float2* pc = reinterpret_cast<const float2*>(pred_coords) + (size_t)b * NQ;
        #pragma unroll
        for (int t = 0; t < 2; ++t) {
            int g = g0 + wv * 2 + t;
            int m = gt_masks[b * NG + g];
            u64 kk[4] = {~0ull, ~0ull, ~0ull, ~0ull};
            if (m) {
                int c  = gt_labels[b * NG + g];
                int bc = b * NC + c;
                float2 gc = reinterpret_cast<const float2*>(gt_coords)[(size_t)b * NG + g];
                float gx = gc.x, gy = gc.y, gb2 = gc.x * gc.x + gc.y * gc.y;
                unsigned n = count[bc];                 // <= NQ by construction
                const u64* lst = clist + ((size_t)bc << 14);
                for (unsigned j = lane; j < n; j += 64) {
                    u64 e = lst[j];
                    float p = __uint_as_float((unsigned)(e >> 32));
                    unsigned q = (unsigned)(e & 0xFFFFFFFFu);
                    float2 cq = pc[q];
                    float a2 = cq.x * cq.x + cq.y * cq.y;
                    float ab = cq.x * gx + cq.y * gy;
                    float d2 = fmaxf(a2 + gb2 - 2.0f * ab, 0.0f);
                    float cost = 0.1f * sqrtf(d2) - p;
                    unsigned uu = __float_as_uint(cost);
                    uu ^= ((unsigned)((int)uu >> 31)) | 0x80000000u;
                    u64 k = ((u64)uu << 32) | q;
                    if (k < kk[3]) { kk[3] = k; ce(kk[2], kk[3]); ce(kk[1], kk[2]); ce(kk[0], kk[1]); }
                }
                #pragma unroll
                for (int d = 1; d < 64; d <<= 1) {
                    u64 b0 = __shfl_xor(kk[0], d, 64);
                    u64 b1 = __shfl_xor(kk[1], d, 64);
                    u64 b2 = __shfl_xor(kk[2], d, 64);
                    u64 b3 = __shfl_xor(kk[3], d, 64);
                    merge4(kk, b0, b1, b2, b3);
                }
            }
            if (lane < 4) {
                u64 sel = (lane == 0) ? kk[0] : (lane == 1) ? kk[1] : (lane == 2) ? kk[2] : kk[3];
                int idx = m ? (int)(sel & 0xFFFFFFFFull) : lane;
                out[((size_t)(b * 4 + lane) << 10) + g] = idx;
            }
        }
    }
}

extern "C" void kernel_launch(void* const* d_in, const int* in_sizes, int n_in,
                              void* d_out, int out_size, void* d_ws, size_t ws_size,
                              hipStream_t stream) {
    const float* pred_coords = (const float*)d_in[0];
    const float* pred_logits = (const float*)d_in[1];
    const float* gt_coords   = (const float*)d_in[2];
    const int*   gt_labels   = (const int*)d_in[3];
    const int*   gt_masks    = (const int*)d_in[4];
    int* out = (int*)d_out;

    char* ws = (char*)d_ws;
    unsigned* ctrs     = (unsigned*)(ws + 0);        // 3 u32
    unsigned* count    = (unsigned*)(ws + 64);       // 40 u32
    float*    T        = (float*)(ws + 256);         // 40 f32
    float*    partials = (float*)(ws + 512);         // 640*4 f32 = 10240 B
    float*    probs    = (float*)(ws + 16384);       // 40*16384 f32 = 2.62 MB
    u64*      clist    = (u64*)(ws + (4u << 20));    // 40*16384 u64 = 5.24 MB

    // zero barrier counters + candidate counts (replayed every graph iteration)
    hipMemsetAsync(ws, 0, 256, stream);
    fused_kernel<<<GRID, THREADS, 0, stream>>>(
        pred_coords, pred_logits, gt_coords, gt_labels, gt_masks,
        ctrs, count, T, partials, probs, clist, out);
}

// Round 4
// 52.835 us; speedup vs baseline: 6.3449x; 6.3449x over previous
//
#include <hip/hip_runtime.h>
#include <cstdint>
#include <cstddef>

#define BS 8
#define NQ 16384
#define NG 1024
#define NC 5
#define NBC 40
#define THREADS 256
#define GRID 512            // 2 blocks/CU on 256 CUs -> co-resident
#define CSLOTS 64           // clist capacity per (bc, chunk)
#define SLACK 0.1514214f    // 0.1*sqrt(2) + 0.01 margin
#define FINF 3.0e38f

using u64 = unsigned long long;
#define AGENT __HIP_MEMORY_SCOPE_AGENT

// agent-scope (cache-bypassing, coherent-point) accessors for cross-block data
__device__ __forceinline__ float aload_f(const float* p) {
    return __hip_atomic_load(p, __ATOMIC_RELAXED, AGENT);
}
__device__ __forceinline__ void astore_f(float* p, float v) {
    __hip_atomic_store(p, v, __ATOMIC_RELAXED, AGENT);
}
__device__ __forceinline__ unsigned aload_u(const unsigned* p) {
    return __hip_atomic_load(p, __ATOMIC_RELAXED, AGENT);
}
__device__ __forceinline__ void astore_u(unsigned* p, unsigned v) {
    __hip_atomic_store(p, v, __ATOMIC_RELAXED, AGENT);
}
__device__ __forceinline__ u64 aload_u64(const u64* p) {
    return __hip_atomic_load(p, __ATOMIC_RELAXED, AGENT);
}
__device__ __forceinline__ void astore_u64(u64* p, u64 v) {
    __hip_atomic_store(p, v, __ATOMIC_RELAXED, AGENT);
}

// ---------- float top-4 (keep 4 smallest, sorted ascending) ----------
__device__ __forceinline__ void fce(float &x, float &y) {
    float lo = fminf(x, y), hi = fmaxf(x, y);
    x = lo; y = hi;
}
__device__ __forceinline__ void finsert(float k[4], float v) {
    float c = v, t;
    t = fminf(k[0], c); c = fmaxf(k[0], c); k[0] = t;
    t = fminf(k[1], c); c = fmaxf(k[1], c); k[1] = t;
    t = fminf(k[2], c); c = fmaxf(k[2], c); k[2] = t;
    k[3] = fminf(k[3], c);
}
__device__ __forceinline__ void fmerge4(float a[4], float b0, float b1, float b2, float b3) {
    float m0 = fminf(a[0], b3), m1 = fminf(a[1], b2), m2 = fminf(a[2], b1), m3 = fminf(a[3], b0);
    fce(m0, m2); fce(m1, m3); fce(m0, m1); fce(m2, m3);
    a[0] = m0; a[1] = m1; a[2] = m2; a[3] = m3;
}

// ---------- u64 keyed top-4 (exact, tie-break by low 32 = q) ----------
__device__ __forceinline__ void ce(u64 &x, u64 &y) {
    u64 lo = x < y ? x : y;
    u64 hi = x < y ? y : x;
    x = lo; y = hi;
}
__device__ __forceinline__ void merge4(u64 a[4], u64 b0, u64 b1, u64 b2, u64 b3) {
    u64 m0 = a[0] < b3 ? a[0] : b3;
    u64 m1 = a[1] < b2 ? a[1] : b2;
    u64 m2 = a[2] < b1 ? a[2] : b1;
    u64 m3 = a[3] < b0 ? a[3] : b0;
    ce(m0, m2); ce(m1, m3); ce(m0, m1); ce(m2, m3);
    a[0] = m0; a[1] = m1; a[2] = m2; a[3] = m3;
}
__device__ __forceinline__ void kinsert(u64 kk[4], float cost, unsigned q) {
    unsigned uu = __float_as_uint(cost);
    uu ^= ((unsigned)((int)uu >> 31)) | 0x80000000u;
    u64 k = ((u64)uu << 32) | q;
    if (k < kk[3]) { kk[3] = k; ce(kk[2], kk[3]); ce(kk[1], kk[2]); ce(kk[0], kk[1]); }
}

#define SOFTMAX5(lg, X0, X1, X2, X3, X4, S)                                     \
    float X0 = (lg)[0], X1 = (lg)[1], X2 = (lg)[2], X3 = (lg)[3], X4 = (lg)[4]; \
    {                                                                           \
        float mx_ = fmaxf(fmaxf(fmaxf(X0, X1), fmaxf(X2, X3)), X4);             \
        X0 = expf(X0 - mx_); X1 = expf(X1 - mx_); X2 = expf(X2 - mx_);          \
        X3 = expf(X3 - mx_); X4 = expf(X4 - mx_);                               \
    }                                                                           \
    float S = X0 + X1 + X2 + X3 + X4;

// tree grid-barrier: 512 -> 64 leaves(8 each) -> 8 mids(8 each) -> master(8).
// counters 128B apart, zeroed by memset node each replay. No cache fences:
// all cross-block data moves via agent-scope (bypass) accessors.
__device__ __forceinline__ void gridbar(unsigned* base, int blk, int tid) {
    __syncthreads();                        // drains each wave's vmem ops
    if (tid == 0) {
        int leafid = blk & 63;
        unsigned* leaf   = base + leafid * 32;           // 128B apart
        unsigned* mid    = base + 2048 + (leafid >> 3) * 32;
        unsigned* master = base + 2304;
        unsigned o = __hip_atomic_fetch_add(leaf, 1u, __ATOMIC_RELEASE, AGENT);
        if (o == 7u) {
            unsigned o2 = __hip_atomic_fetch_add(mid, 1u, __ATOMIC_RELEASE, AGENT);
            if (o2 == 7u)
                __hip_atomic_fetch_add(master, 1u, __ATOMIC_RELEASE, AGENT);
        }
        for (long s = 0; s < (1L << 22); ++s) {          // bounded spin safety net
            if (__hip_atomic_load(master, __ATOMIC_RELAXED, AGENT) >= 8u) break;
            __builtin_amdgcn_s_sleep(8);
        }
    }
    __syncthreads();
}

__global__ __launch_bounds__(THREADS, 2) void fused_kernel(
        const float* __restrict__ pred_coords,   // [BS][NQ][2]
        const float* __restrict__ logits,        // [BS][NQ][NC]
        const float* __restrict__ gt_coords,     // [BS][NG][2]
        const int*   __restrict__ gt_labels,     // [BS][NG]
        const int*   __restrict__ gt_masks,      // [BS][NG]
        unsigned*    __restrict__ bar0,
        unsigned*    __restrict__ bar1,
        unsigned*    __restrict__ ccount,        // [NBC][64]
        float*       __restrict__ partials,      // [BS][64][NC][4]
        u64*         __restrict__ clist,         // [NBC][64][CSLOTS]
        int*         __restrict__ out)           // [BS][4][NG]
{
    const int blk = blockIdx.x, tid = threadIdx.x;
    const int wv = tid >> 6, lane = tid & 63;
    const int b = blk >> 6, chunk = blk & 63;
    const int q = (chunk << 8) + tid;

    __shared__ float slds[4][NC][4];

    // ---------------- phase A: softmax once per q; block top-4 per class ----------------
    const float* lg = logits + ((size_t)b * NQ + q) * NC;
    SOFTMAX5(lg, x0, x1, x2, x3, x4, s);
    float p0 = x0 / s, p1 = x1 / s, p2 = x2 / s, p3 = x3 / s, p4 = x4 / s;

    {
        float nk[NC][4];
        nk[0][0] = -p0; nk[1][0] = -p1; nk[2][0] = -p2; nk[3][0] = -p3; nk[4][0] = -p4;
        #pragma unroll
        for (int c = 0; c < NC; ++c) { nk[c][1] = FINF; nk[c][2] = FINF; nk[c][3] = FINF; }
        #pragma unroll
        for (int d = 1; d < 64; d <<= 1) {
            #pragma unroll
            for (int c = 0; c < NC; ++c) {
                float b0 = __shfl_xor(nk[c][0], d, 64);
                float b1 = __shfl_xor(nk[c][1], d, 64);
                float b2 = __shfl_xor(nk[c][2], d, 64);
                float b3 = __shfl_xor(nk[c][3], d, 64);
                fmerge4(nk[c], b0, b1, b2, b3);
            }
        }
        if (lane == 0) {
            #pragma unroll
            for (int c = 0; c < NC; ++c)
                #pragma unroll
                for (int j = 0; j < 4; ++j) slds[wv][c][j] = nk[c][j];
        }
        __syncthreads();
        if (tid < NC) {                      // one thread per class finalizes
            float a[4] = {slds[0][tid][0], slds[0][tid][1], slds[0][tid][2], slds[0][tid][3]};
            #pragma unroll
            for (int w = 1; w < 4; ++w)
                fmerge4(a, slds[w][tid][0], slds[w][tid][1], slds[w][tid][2], slds[w][tid][3]);
            float* pp = partials + ((size_t)(b * 64 + chunk) * NC + tid) * 4;
            #pragma unroll
            for (int j = 0; j < 4; ++j) astore_f(&pp[j], a[j]);
        }
    }

    gridbar(bar0, blk, tid);

    // ---------------- phase B: per-wave redundant threshold; ballot-rank compact ----------------
    float Tc[NC];
    {
        #pragma unroll
        for (int c = 0; c < NC; ++c) {
            const float* pp = partials + ((size_t)(b * 64 + lane) * NC + c) * 4;
            float a[4] = {FINF, FINF, FINF, FINF};
            #pragma unroll
            for (int j = 0; j < 4; ++j) finsert(a, aload_f(&pp[j]));
            #pragma unroll
            for (int d = 1; d < 64; d <<= 1) {
                float b0 = __shfl_xor(a[0], d, 64);
                float b1 = __shfl_xor(a[1], d, 64);
                float b2 = __shfl_xor(a[2], d, 64);
                float b3 = __shfl_xor(a[3], d, 64);
                fmerge4(a, b0, b1, b2, b3);
            }
            Tc[c] = -a[3] - SLACK;           // P4* - slack
        }
    }
    __shared__ unsigned wcnt[4];
    #pragma unroll
    for (int c = 0; c < NC; ++c) {
        float p = (c == 0) ? p0 : (c == 1) ? p1 : (c == 2) ? p2 : (c == 3) ? p3 : p4;
        bool pass = (p >= Tc[c]);
        u64 m = __ballot(pass);
        if (lane == 0) wcnt[wv] = (unsigned)__popcll(m);
        __syncthreads();
        unsigned pre = 0, tot = 0;
        #pragma unroll
        for (int w = 0; w < 4; ++w) { unsigned v = wcnt[w]; if (w < wv) pre += v; tot += v; }
        int bc = b * NC + c;
        if (pass) {
            unsigned rank = pre + (unsigned)__popcll(m & ((1ull << lane) - 1ull));
            if (rank < CSLOTS)
                astore_u64(&clist[((size_t)bc * 64 + chunk) * CSLOTS + rank],
                           ((u64)__float_as_uint(p) << 32) | (unsigned)q);
        }
        if (tid == 0) astore_u(&ccount[bc * 64 + chunk], tot);   // tot>CSLOTS = overflow flag
        __syncthreads();
    }

    gridbar(bar1, blk, tid);

    // ---------------- phase C: exact keyed top-4 per gt (1 gt per wave, 4 rounds) ----------------
    #pragma unroll
    for (int t = 0; t < 4; ++t) {
        int gidx = t * 2048 + blk * 4 + wv;
        int b2 = gidx >> 10, g = gidx & 1023;
        int m = gt_masks[b2 * NG + g];
        u64 kk[4] = {~0ull, ~0ull, ~0ull, ~0ull};
        if (m) {
            int c  = gt_labels[b2 * NG + g];
            int bc = b2 * NC + c;
            float2 gc = reinterpret_cast<const float2*>(gt_coords)[(size_t)b2 * NG + g];
            float gx = gc.x, gy = gc.y, gb2 = gc.x * gc.x + gc.y * gc.y;
            const float2* pc = reinterpret_cast<const float2*>(pred_coords) + (size_t)b2 * NQ;
            unsigned n = aload_u(&ccount[bc * 64 + lane]);       // lane = chunk
            u64 ov = __ballot(n > CSLOTS);
            if (ov == 0) {
                const u64* lst = clist + ((size_t)bc * 64 + lane) * CSLOTS;
                for (unsigned j = 0; j < n; ++j) {
                    u64 e = aload_u64(&lst[j]);
                    float p = __uint_as_float((unsigned)(e >> 32));
                    unsigned qq = (unsigned)(e & 0xFFFFFFFFu);
                    float2 cq = pc[qq];
                    float a2 = cq.x * cq.x + cq.y * cq.y;
                    float ab = cq.x * gx + cq.y * gy;
                    float d2 = fmaxf(a2 + gb2 - 2.0f * ab, 0.0f);
                    kinsert(kk, 0.1f * sqrtf(d2) - p, qq);
                }
            } else {
                // overflow fallback: exact brute scan (recompute softmax; same numerics)
                for (int q2 = lane; q2 < NQ; q2 += 64) {
                    const float* lg2 = logits + ((size_t)b2 * NQ + q2) * NC;
                    SOFTMAX5(lg2, y0, y1, y2, y3, y4, s2);
                    float num = (c == 0) ? y0 : (c == 1) ? y1 : (c == 2) ? y2 : (c == 3) ? y3 : y4;
                    float p = num / s2;
                    float2 cq = pc[q2];
                    float a2 = cq.x * cq.x + cq.y * cq.y;
                    float ab = cq.x * gx + cq.y * gy;
                    float d2 = fmaxf(a2 + gb2 - 2.0f * ab, 0.0f);
                    kinsert(kk, 0.1f * sqrtf(d2) - p, (unsigned)q2);
                }
            }
            #pragma unroll
            for (int d = 1; d < 64; d <<= 1) {
                u64 b0 = __shfl_xor(kk[0], d, 64);
                u64 b1 = __shfl_xor(kk[1], d, 64);
                u64 b2_ = __shfl_xor(kk[2], d, 64);
                u64 b3 = __shfl_xor(kk[3], d, 64);
                merge4(kk, b0, b1, b2_, b3);
            }
        }
        if (lane < 4) {
            u64 sel = (lane == 0) ? kk[0] : (lane == 1) ? kk[1] : (lane == 2) ? kk[2] : kk[3];
            int idx = m ? (int)(sel & 0xFFFFFFFFull) : lane;
            out[((size_t)(b2 * 4 + lane) << 10) + g] = idx;
        }
    }
}

extern "C" void kernel_launch(void* const* d_in, const int* in_sizes, int n_in,
                              void* d_out, int out_size, void* d_ws, size_t ws_size,
                              hipStream_t stream) {
    const float* pred_coords = (const float*)d_in[0];
    const float* pred_logits = (const float*)d_in[1];
    const float* gt_coords   = (const float*)d_in[2];
    const int*   gt_labels   = (const int*)d_in[3];
    const int*   gt_masks    = (const int*)d_in[4];
    int* out = (int*)d_out;

    char* ws = (char*)d_ws;
    unsigned* bar0     = (unsigned*)(ws + 0);        // 64 leaves + 8 mids + master, 128B apart
    unsigned* bar1     = (unsigned*)(ws + 16384);
    unsigned* ccount   = (unsigned*)(ws + 32768);    // 40*64 u32 = 10 KB (fully rewritten/run)
    float*    partials = (float*)(ws + 49152);       // 8*64*5*4 f32 = 40 KB (fully rewritten/run)
    u64*      clist    = (u64*)(ws + 98304);         // 40*64*64 u64 = 1.31 MB

    hipMemsetAsync(ws, 0, 32768, stream);            // zero barrier counters each replay
    fused_kernel<<<GRID, THREADS, 0, stream>>>(
        pred_coords, pred_logits, gt_coords, gt_labels, gt_masks,
        bar0, bar1, ccount, partials, clist, out);
}